// Round 4
// baseline (329.622 us; speedup 1.0000x reference)
//
#include <hip/hip_runtime.h>

// RWKV6 TimeMix on MI355X — R4: bf16 intermediates + recompute-style scan.
//   K0 prep_w     : 5 weight matrices fp32 -> bf16
//   K1 prep_mix   : token-shift mix -> xr,xk,xv,xw (bf16)
//   K2 gemm4_bt   : 4x MFMA GEMM + activations -> r,k,v (bf16), w (fp32)
//   K3 scan_state : chunked (C=64) state-only scan -> U_c, D_c
//   K4 state_prop : S_{c+1} = D_c*S_c + U_c (U slot becomes chunk-initial S_c)
//   K5 scan_out   : full recurrence from S_c, fused group-LN + r-gate -> oh (bf16)
//   K6 gemm_out   : MFMA GEMM -> d_out (fp32)
//
// Shapes: B=4, T=1024, D=1024, H=16, DH=64. Chunks: NC=16, C=64.

typedef unsigned short u16;
typedef unsigned int   u32;

typedef __attribute__((ext_vector_type(8))) __bf16 bf16x8;
typedef __attribute__((ext_vector_type(4))) float   f32x4;

#define MB (1u << 20)

#define LDS_PTR(p) ((__attribute__((address_space(3))) void*)(p))
#define GLB_PTR(p) ((const __attribute__((address_space(1))) void*)(p))

__device__ __forceinline__ u16 f2bf(float f) {
  u32 u = __builtin_bit_cast(u32, f);
  u += 0x7FFFu + ((u >> 16) & 1u);   // RNE; inputs are finite
  return (u16)(u >> 16);
}
__device__ __forceinline__ float bf2f(u16 x) {
  u32 u = ((u32)x) << 16;
  return __builtin_bit_cast(float, u);
}
__device__ __forceinline__ u32 pack2(float a, float b) {
  return (u32)f2bf(a) | ((u32)f2bf(b) << 16);
}

// ---------------- K0: weights fp32 -> bf16 (5 x 1M elements, 2-wide) --------
__global__ __launch_bounds__(256) void prep_w(
    const float* __restrict__ w0, const float* __restrict__ w1,
    const float* __restrict__ w2, const float* __restrict__ w3,
    const float* __restrict__ w4, u32* __restrict__ out) {
  int idx = blockIdx.x * 256 + threadIdx.x;   // pair index, 5*524288 total
  int m = idx >> 19;                          // matrix id (uniform per block)
  int l = idx & 524287;
  const float* src = (m == 0) ? w0 : (m == 1) ? w1 : (m == 2) ? w2 : (m == 3) ? w3 : w4;
  float2 v = *(const float2*)(src + (size_t)l * 2);
  out[idx] = pack2(v.x, v.y);
}

// ---------------- K1: token-shift mix -> bf16 (2-wide) ----------------------
__global__ __launch_bounds__(256) void prep_mix(
    const float* __restrict__ x,
    const float* __restrict__ tmr, const float* __restrict__ tmk,
    const float* __restrict__ tmv, const float* __restrict__ tmw,
    u32* __restrict__ xr, u32* __restrict__ xk,
    u32* __restrict__ xv, u32* __restrict__ xw) {
  int idx = blockIdx.x * 256 + threadIdx.x;   // pair index over 4*1024*512
  int t  = (idx >> 9) & 1023;
  int d0 = (idx & 511) * 2;
  size_t e = (size_t)idx * 2;
  float2 xc = *(const float2*)(x + e);
  float2 xp = make_float2(0.f, 0.f);
  if (t > 0) xp = *(const float2*)(x + e - 1024);
  float2 tm;
  tm = *(const float2*)(tmr + d0);
  xr[idx] = pack2(tm.x * xc.x + (1.f - tm.x) * xp.x, tm.y * xc.y + (1.f - tm.y) * xp.y);
  tm = *(const float2*)(tmk + d0);
  xk[idx] = pack2(tm.x * xc.x + (1.f - tm.x) * xp.x, tm.y * xc.y + (1.f - tm.y) * xp.y);
  tm = *(const float2*)(tmv + d0);
  xv[idx] = pack2(tm.x * xc.x + (1.f - tm.x) * xp.x, tm.y * xc.y + (1.f - tm.y) * xp.y);
  tm = *(const float2*)(tmw + d0);
  xw[idx] = pack2(tm.x * xc.x + (1.f - tm.x) * xp.x, tm.y * xc.y + (1.f - tm.y) * xp.y);
}

// ---------------- GEMM core: C[m][n] = sum_k A[m][k]*W[n][k] ----------------
// Tile 128x128xBK32, 256 threads. Triple-buffered global_load_lds pipeline
// (raw s_barrier + manual vmcnt, never vmcnt(0) in steady state). XOR-swizzled
// LDS. Grid: x = m-tile, y = n-tile (same-A blocks stride-8 -> same XCD).
// ACT: 0 none, 1 sigmoid, 2 -softplus(-z)-1e-4.  OBF: 1 -> store bf16.
template <int ACT, int OBF>
__device__ __forceinline__ void gemm_core(
    const u16* __restrict__ A, const u16* __restrict__ W, void* __restrict__ Optr,
    u16* Asm, u16* Bsm) {   // each 3*4096 u16 (3 x 8KB)
  int tid = threadIdx.x;
  int m0 = blockIdx.x * 128, n0 = blockIdx.y * 128;
  int wave = tid >> 6, lane = tid & 63;
  int wm = (wave >> 1) * 64, wn = (wave & 1) * 64;
  int r16 = lane & 15, quad = lane >> 4;

  f32x4 acc[4][4] = {};

  int srow0 = wave * 32 + (lane >> 2);
  int srow1 = srow0 + 16;
  int c4    = lane & 3;
  int q0 = c4 ^ ((srow0 >> 1) & 3);
  int q1 = c4 ^ ((srow1 >> 1) & 3);
  const u16* Ag0 = A + (size_t)(m0 + srow0) * 1024 + q0 * 8;
  const u16* Ag1 = A + (size_t)(m0 + srow1) * 1024 + q1 * 8;
  const u16* Bg0 = W + (size_t)(n0 + srow0) * 1024 + q0 * 8;
  const u16* Bg1 = W + (size_t)(n0 + srow1) * 1024 + q1 * 8;
  int ldsOff0 = wave * 1024;        // u16 offset within one 8KB buffer
  int ldsOff1 = wave * 1024 + 512;

  int aoff[4], boff[4];
#pragma unroll
  for (int mt = 0; mt < 4; ++mt) {
    int r = wm + mt * 16 + r16;
    aoff[mt] = r * 32 + (quad ^ ((r >> 1) & 3)) * 8;
  }
#pragma unroll
  for (int nt = 0; nt < 4; ++nt) {
    int r = wn + nt * 16 + r16;
    boff[nt] = r * 32 + (quad ^ ((r >> 1) & 3)) * 8;
  }

#define ISSUE_TILE(t, buf)                                                              \
  do {                                                                                  \
    int _o = (buf) * 4096, _k = (t) * 32;                                               \
    __builtin_amdgcn_global_load_lds(GLB_PTR(Ag0 + _k), LDS_PTR(Asm + _o + ldsOff0), 16, 0, 0); \
    __builtin_amdgcn_global_load_lds(GLB_PTR(Ag1 + _k), LDS_PTR(Asm + _o + ldsOff1), 16, 0, 0); \
    __builtin_amdgcn_global_load_lds(GLB_PTR(Bg0 + _k), LDS_PTR(Bsm + _o + ldsOff0), 16, 0, 0); \
    __builtin_amdgcn_global_load_lds(GLB_PTR(Bg1 + _k), LDS_PTR(Bsm + _o + ldsOff1), 16, 0, 0); \
  } while (0)

  ISSUE_TILE(0, 0);
  ISSUE_TILE(1, 1);
  ISSUE_TILE(2, 2);

  int cur = 0;
  for (int i = 0; i < 32; ++i) {
    if (i < 30)       asm volatile("s_waitcnt vmcnt(8)" ::: "memory");
    else if (i == 30) asm volatile("s_waitcnt vmcnt(4)" ::: "memory");
    else              asm volatile("s_waitcnt vmcnt(0)" ::: "memory");
    __builtin_amdgcn_s_barrier();   // all waves' tile-i data landed

    const u16* As = Asm + cur * 4096;
    const u16* Bs = Bsm + cur * 4096;
    bf16x8 af[4], bfm[4];
#pragma unroll
    for (int mt = 0; mt < 4; ++mt) af[mt] = *(const bf16x8*)&As[aoff[mt]];
#pragma unroll
    for (int nt = 0; nt < 4; ++nt) bfm[nt] = *(const bf16x8*)&Bs[boff[nt]];
#pragma unroll
    for (int mt = 0; mt < 4; ++mt)
#pragma unroll
      for (int nt = 0; nt < 4; ++nt)
        acc[mt][nt] = __builtin_amdgcn_mfma_f32_16x16x32_bf16(af[mt], bfm[nt], acc[mt][nt], 0, 0, 0);

    asm volatile("s_waitcnt lgkmcnt(0)" ::: "memory");  // my ds_reads done
    __builtin_amdgcn_s_barrier();                       // everyone's reads done
    if (i + 3 < 32) ISSUE_TILE(i + 3, cur);             // re-target freed buffer
    cur = (cur == 2) ? 0 : cur + 1;
  }
#undef ISSUE_TILE

  // epilogue: C/D layout col=lane&15, row=quad*4+reg  [verified m89/m91]
#pragma unroll
  for (int mt = 0; mt < 4; ++mt) {
#pragma unroll
    for (int nt = 0; nt < 4; ++nt) {
#pragma unroll
      for (int rg = 0; rg < 4; ++rg) {
        int row = m0 + wm + mt * 16 + quad * 4 + rg;
        int col = n0 + wn + nt * 16 + r16;
        float v = acc[mt][nt][rg];
        if (ACT == 1) v = 1.f / (1.f + __expf(-v));
        else if (ACT == 2) v = -(fmaxf(-v, 0.f) + log1pf(expf(-fabsf(v)))) - 1e-4f;
        size_t idx = (size_t)row * 1024 + col;
        if (OBF) ((u16*)Optr)[idx] = f2bf(v);
        else     ((float*)Optr)[idx] = v;
      }
    }
  }
}

// K2: four projection GEMMs in one launch (grid.z selects matrix)
__global__ __launch_bounds__(256) void gemm4_bt(
    const u16* __restrict__ xr, const u16* __restrict__ xk,
    const u16* __restrict__ xv, const u16* __restrict__ xw,
    const u16* __restrict__ Wr, const u16* __restrict__ Wk,
    const u16* __restrict__ Wv, const u16* __restrict__ Ww,
    u16* __restrict__ r, u16* __restrict__ k,
    u16* __restrict__ v, float* __restrict__ w) {
  __shared__ __align__(16) u16 Asm[3 * 4096];
  __shared__ __align__(16) u16 Bsm[3 * 4096];
  switch (blockIdx.z) {
    case 0:  gemm_core<1, 1>(xr, Wr, r, Asm, Bsm); break;   // r = sigmoid, bf16
    case 1:  gemm_core<0, 1>(xk, Wk, k, Asm, Bsm); break;   // k bf16
    case 2:  gemm_core<0, 1>(xv, Wv, v, Asm, Bsm); break;   // v bf16
    default: gemm_core<2, 0>(xw, Ww, w, Asm, Bsm); break;   // w fp32 (decay path)
  }
}

// K6: output GEMM
__global__ __launch_bounds__(256) void gemm_out(
    const u16* __restrict__ A, const u16* __restrict__ W, float* __restrict__ O) {
  __shared__ __align__(16) u16 Asm[3 * 4096];
  __shared__ __align__(16) u16 Bsm[3 * 4096];
  gemm_core<0, 0>(A, W, O, Asm, Bsm);
}

// ---------------- K3: state-only intra-chunk scan ---------------------------
// Block = (chunk c, b*16+h), 256 threads = 4 i-groups x 64 j.
// Thread (ig,j) owns s[i][j], i in [ig*16, ig*16+16). Loader roles:
// w0 -> v, w1 -> k, w2 -> w (exp + per-lane D cumprod), w3 -> none.
// s update only: s = ew*s + k*v.  Outputs U_c (final local state), D_c.
__global__ __launch_bounds__(256) void scan_state(
    const u16* __restrict__ kb, const u16* __restrict__ vb,
    const float* __restrict__ wb,
    float* __restrict__ U, float* __restrict__ Dc) {
  int c = blockIdx.x, bh = blockIdx.y;
  int b = bh >> 4, h = bh & 15;
  int tid = threadIdx.x, ig = tid >> 6, j = tid & 63;

  __shared__ __align__(16) float2 combo2[2][64];  // per-i: (k, exp(w))
  __shared__ float vsb[2][64];

  float s[16];
#pragma unroll
  for (int ii = 0; ii < 16; ++ii) s[ii] = 0.f;

  size_t base = ((size_t)(b * 1024 + c * 64)) * 1024 + h * 64 + j;
  float dloc = 1.0f;

  // stage t=0 into buf 0
  if (ig == 0)      vsb[0][j] = bf2f(vb[base]);
  else if (ig == 1) combo2[0][j].x = bf2f(kb[base]);
  else if (ig == 2) combo2[0][j].y = __expf(wb[base]);
  __syncthreads();

  for (int t = 0; t < 64; ++t) {
    int buf = t & 1, nbuf = buf ^ 1;
    if (t < 63) {
      size_t idx = base + (size_t)(t + 1) * 1024;
      if (ig == 0)      vsb[nbuf][j] = bf2f(vb[idx]);
      else if (ig == 1) combo2[nbuf][j].x = bf2f(kb[idx]);
      else if (ig == 2) combo2[nbuf][j].y = __expf(wb[idx]);
    }
    if (ig == 2) dloc *= combo2[buf][j].y;
    float vj = vsb[buf][j];
#pragma unroll
    for (int p = 0; p < 8; ++p) {
      float4 kw2 = *(const float4*)&combo2[buf][ig * 16 + p * 2];  // k0,ew0,k1,ew1
      s[p * 2]     = fmaf(kw2.y, s[p * 2],     kw2.x * vj);
      s[p * 2 + 1] = fmaf(kw2.w, s[p * 2 + 1], kw2.z * vj);
    }
    __syncthreads();
  }

  float* Ug = U + (size_t)(bh * 16 + c) * 4096;
#pragma unroll
  for (int ii = 0; ii < 16; ++ii) Ug[(ig * 16 + ii) * 64 + j] = s[ii];
  if (ig == 2) Dc[(bh * 16 + c) * 64 + j] = dloc;
}

// ---------------- K4: chunk-state propagation (per-element parallel) --------
__global__ __launch_bounds__(256) void state_prop(
    float* __restrict__ U, const float* __restrict__ Dc) {
  int bh  = blockIdx.x >> 4;
  int e   = (blockIdx.x & 15) * 256 + threadIdx.x;  // 0..4095
  int i   = e >> 6;                                 // state row (decay index)
  float acc = 0.f;
  for (int c = 0; c < 16; ++c) {
    float* Ug = U + (size_t)(bh * 16 + c) * 4096 + e;
    float d = Dc[(bh * 16 + c) * 64 + i];
    float uv = *Ug;
    *Ug = acc;                      // write S_c (chunk-initial state)
    acc = fmaf(d, acc, uv);         // S_{c+1} = D_c*S_c + U_c
  }
}

// ---------------- K5: output scan from true S_c + group-LN + gate -> bf16 ---
// Exact recurrence restarted from S_c: o_t = r_t·(s + exp(u+k_t) v_t), then
// s = ew*s + k v. Wave (t&3) assembles o_t, does LN over 64 lanes, gates by
// r_t, stores bf16. Loader roles: w0 -> r, w1 -> k(+euk), w2 -> v, w3 -> ew.
__global__ __launch_bounds__(256) void scan_out(
    const u16* __restrict__ rb, const u16* __restrict__ kb,
    const u16* __restrict__ vb, const float* __restrict__ wb,
    const float* __restrict__ u, const float* __restrict__ S,
    const float* __restrict__ lnw, const float* __restrict__ lnb,
    u16* __restrict__ oh) {
  int c = blockIdx.x, bh = blockIdx.y;
  int b = bh >> 4, h = bh & 15;
  int tid = threadIdx.x, ig = tid >> 6, j = tid & 63;

  __shared__ __align__(16) float4 combo[2][64];  // per-i: (r, k, exp(u+k), exp(w))
  __shared__ float vsb[2][64];
  __shared__ float part[2][4][64];

  // init state from true chunk-initial S_c
  const float* Sg = S + (size_t)(bh * 16 + c) * 4096;
  float s[16];
#pragma unroll
  for (int ii = 0; ii < 16; ++ii) s[ii] = Sg[(ig * 16 + ii) * 64 + j];

  size_t base = ((size_t)(b * 1024 + c * 64)) * 1024 + h * 64 + j;
  float uval = (ig == 1) ? u[h * 64 + j] : 0.f;
  float lw = lnw[j], lb = lnb[j];

  // stage t=0 into buf 0
  if (ig == 0)      combo[0][j].x = bf2f(rb[base]);
  else if (ig == 1) { float kv = bf2f(kb[base]); combo[0][j].y = kv; combo[0][j].z = __expf(uval + kv); }
  else if (ig == 2) vsb[0][j] = bf2f(vb[base]);
  else              combo[0][j].w = __expf(wb[base]);
  __syncthreads();

  for (int t = 0; t < 64; ++t) {
    int buf = t & 1, nbuf = buf ^ 1;
    if (t < 63) {
      size_t idx = base + (size_t)(t + 1) * 1024;
      if (ig == 0)      combo[nbuf][j].x = bf2f(rb[idx]);
      else if (ig == 1) { float kv = bf2f(kb[idx]); combo[nbuf][j].y = kv; combo[nbuf][j].z = __expf(uval + kv); }
      else if (ig == 2) vsb[nbuf][j] = bf2f(vb[idx]);
      else              combo[nbuf][j].w = __expf(wb[idx]);
    }
    float rg = combo[buf][j].x;   // r_t[j] gate (read pre-barrier; buf stable)
    float vj = vsb[buf][j];
    float acc = 0.f;
#pragma unroll
    for (int ii = 0; ii < 16; ++ii) {
      float4 cb = combo[buf][ig * 16 + ii];
      float tmp = fmaf(cb.z, vj, s[ii]);     // s + exp(u+k)*v
      acc = fmaf(cb.x, tmp, acc);            // += r * (...)
      s[ii] = fmaf(cb.w, s[ii], cb.y * vj);  // s = exp(w)*s + k*v
    }
    part[buf][ig][j] = acc;
    __syncthreads();
    if (ig == (t & 3)) {
      float ot = part[buf][0][j] + part[buf][1][j] + part[buf][2][j] + part[buf][3][j];
      float s1 = ot, s2 = ot * ot;
#pragma unroll
      for (int m = 1; m < 64; m <<= 1) {
        s1 += __shfl_xor(s1, m, 64);
        s2 += __shfl_xor(s2, m, 64);
      }
      float mu = s1 * (1.f / 64.f);
      float var = s2 * (1.f / 64.f) - mu * mu;
      float nv = (ot - mu) * rsqrtf(var + 1e-5f);
      oh[base + (size_t)t * 1024] = f2bf((nv * lw + lb) * rg);
    }
  }
}

// ---------------- launch -----------------------------------------------------
extern "C" void kernel_launch(void* const* d_in, const int* in_sizes, int n_in,
                              void* d_out, int out_size, void* d_ws, size_t ws_size,
                              hipStream_t stream) {
  const float* x    = (const float*)d_in[0];
  const float* W_r  = (const float*)d_in[1];
  const float* W_k  = (const float*)d_in[2];
  const float* W_v  = (const float*)d_in[3];
  const float* W_w  = (const float*)d_in[4];
  const float* W_o  = (const float*)d_in[5];
  const float* u    = (const float*)d_in[6];
  const float* tm_r = (const float*)d_in[7];
  const float* tm_k = (const float*)d_in[8];
  const float* tm_v = (const float*)d_in[9];
  const float* tm_w = (const float*)d_in[10];
  const float* ln_w = (const float*)d_in[11];
  const float* ln_b = (const float*)d_in[12];
  float* out = (float*)d_out;

  char* ws = (char*)d_ws;
  u16* xr = (u16*)(ws + (size_t)0 * MB);
  u16* xk = (u16*)(ws + (size_t)8 * MB);
  u16* xv = (u16*)(ws + (size_t)16 * MB);
  u16* xw = (u16*)(ws + (size_t)24 * MB);
  u16* Wb = (u16*)(ws + (size_t)32 * MB);   // 5 x 2MB: Wr,Wk,Wv,Ww,Wo
  u16* Wrb = Wb;
  u16* Wkb = (u16*)(ws + (size_t)34 * MB);
  u16* Wvb = (u16*)(ws + (size_t)36 * MB);
  u16* Wwb = (u16*)(ws + (size_t)38 * MB);
  u16* Wob = (u16*)(ws + (size_t)40 * MB);
  u16*   rbuf = (u16*)(ws + (size_t)48 * MB);    // 8MB bf16
  u16*   kbuf = (u16*)(ws + (size_t)56 * MB);    // 8MB bf16
  u16*   vbuf = (u16*)(ws + (size_t)64 * MB);    // 8MB bf16
  float* wbuf = (float*)(ws + (size_t)72 * MB);  // 16MB fp32 (decay path)
  float* Ubuf  = (float*)(ws + (size_t)88 * MB); // 16MB (S_c after state_prop)
  float* Dcbuf = (float*)(ws + (size_t)104 * MB);// 256KB
  u16*   ohbuf = (u16*)(ws + (size_t)105 * MB);  // 8MB

  prep_w<<<10240, 256, 0, stream>>>(W_r, W_k, W_v, W_w, W_o, (u32*)Wb);
  prep_mix<<<8192, 256, 0, stream>>>(x, tm_r, tm_k, tm_v, tm_w,
                                     (u32*)xr, (u32*)xk, (u32*)xv, (u32*)xw);
  gemm4_bt<<<dim3(32, 8, 4), 256, 0, stream>>>(xr, xk, xv, xw,
                                               Wrb, Wkb, Wvb, Wwb,
                                               rbuf, kbuf, vbuf, wbuf);
  scan_state<<<dim3(16, 64), 256, 0, stream>>>(kbuf, vbuf, wbuf, Ubuf, Dcbuf);
  state_prop<<<1024, 256, 0, stream>>>(Ubuf, Dcbuf);
  scan_out<<<dim3(16, 64), 256, 0, stream>>>(rbuf, kbuf, vbuf, wbuf, u, Ubuf,
                                             ln_w, ln_b, ohbuf);
  gemm_out<<<dim3(32, 8, 1), 256, 0, stream>>>(ohbuf, Wob, out);
}

// Round 5
// 278.361 us; speedup vs baseline: 1.1842x; 1.1842x over previous
//
#include <hip/hip_runtime.h>

// RWKV6 TimeMix on MI355X — R5: single-pass scan (2-step batching) + MFMA inter.
//   K0 prep_w     : 5 weight matrices fp32 -> bf16
//   K1 prep_mix   : token-shift mix -> xr,xk,xv,xw (bf16)
//   K2 gemm4_bt   : 4x MFMA GEMM + activations -> r,k,v (bf16), w (fp32)
//   K3 scan_intra : chunked (C=64) scan -> o_intra (fp32), rd (bf16), U_c, D_c
//   K4 state_prop : S_{c+1} = D_c*S_c + U_c (U slot becomes chunk-initial S_c)
//   K5 inter_ln   : O = o_intra + RD@S_c (MFMA), group-LN, *r -> oh (bf16)
//   K6 gemm_out   : MFMA GEMM -> d_out (fp32)
//
// Shapes: B=4, T=1024, D=1024, H=16, DH=64. Chunks: NC=16, C=64.

typedef unsigned short u16;
typedef unsigned int   u32;

typedef __attribute__((ext_vector_type(8))) __bf16 bf16x8;
typedef __attribute__((ext_vector_type(4))) float   f32x4;

#define MB (1u << 20)

#define LDS_PTR(p) ((__attribute__((address_space(3))) void*)(p))
#define GLB_PTR(p) ((const __attribute__((address_space(1))) void*)(p))

__device__ __forceinline__ u16 f2bf(float f) {
  u32 u = __builtin_bit_cast(u32, f);
  u += 0x7FFFu + ((u >> 16) & 1u);   // RNE; inputs are finite
  return (u16)(u >> 16);
}
__device__ __forceinline__ float bf2f(u16 x) {
  u32 u = ((u32)x) << 16;
  return __builtin_bit_cast(float, u);
}
__device__ __forceinline__ u32 pack2(float a, float b) {
  return (u32)f2bf(a) | ((u32)f2bf(b) << 16);
}

// ---------------- K0: weights fp32 -> bf16 (5 x 1M elements, 2-wide) --------
__global__ __launch_bounds__(256) void prep_w(
    const float* __restrict__ w0, const float* __restrict__ w1,
    const float* __restrict__ w2, const float* __restrict__ w3,
    const float* __restrict__ w4, u32* __restrict__ out) {
  int idx = blockIdx.x * 256 + threadIdx.x;   // pair index, 5*524288 total
  int m = idx >> 19;                          // matrix id (uniform per block)
  int l = idx & 524287;
  const float* src = (m == 0) ? w0 : (m == 1) ? w1 : (m == 2) ? w2 : (m == 3) ? w3 : w4;
  float2 v = *(const float2*)(src + (size_t)l * 2);
  out[idx] = pack2(v.x, v.y);
}

// ---------------- K1: token-shift mix -> bf16 (2-wide) ----------------------
__global__ __launch_bounds__(256) void prep_mix(
    const float* __restrict__ x,
    const float* __restrict__ tmr, const float* __restrict__ tmk,
    const float* __restrict__ tmv, const float* __restrict__ tmw,
    u32* __restrict__ xr, u32* __restrict__ xk,
    u32* __restrict__ xv, u32* __restrict__ xw) {
  int idx = blockIdx.x * 256 + threadIdx.x;   // pair index over 4*1024*512
  int t  = (idx >> 9) & 1023;
  int d0 = (idx & 511) * 2;
  size_t e = (size_t)idx * 2;
  float2 xc = *(const float2*)(x + e);
  float2 xp = make_float2(0.f, 0.f);
  if (t > 0) xp = *(const float2*)(x + e - 1024);
  float2 tm;
  tm = *(const float2*)(tmr + d0);
  xr[idx] = pack2(tm.x * xc.x + (1.f - tm.x) * xp.x, tm.y * xc.y + (1.f - tm.y) * xp.y);
  tm = *(const float2*)(tmk + d0);
  xk[idx] = pack2(tm.x * xc.x + (1.f - tm.x) * xp.x, tm.y * xc.y + (1.f - tm.y) * xp.y);
  tm = *(const float2*)(tmv + d0);
  xv[idx] = pack2(tm.x * xc.x + (1.f - tm.x) * xp.x, tm.y * xc.y + (1.f - tm.y) * xp.y);
  tm = *(const float2*)(tmw + d0);
  xw[idx] = pack2(tm.x * xc.x + (1.f - tm.x) * xp.x, tm.y * xc.y + (1.f - tm.y) * xp.y);
}

// ---------------- GEMM core: C[m][n] = sum_k A[m][k]*W[n][k] ----------------
// Tile 128x128xBK32, 256 threads. Triple-buffered global_load_lds pipeline
// (raw s_barrier + manual vmcnt, never vmcnt(0) in steady state). XOR-swizzled
// LDS. ACT: 0 none, 1 sigmoid, 2 -softplus(-z)-1e-4.  OBF: 1 -> store bf16.
template <int ACT, int OBF>
__device__ __forceinline__ void gemm_core(
    const u16* __restrict__ A, const u16* __restrict__ W, void* __restrict__ Optr,
    u16* Asm, u16* Bsm) {   // each 3*4096 u16 (3 x 8KB)
  int tid = threadIdx.x;
  int m0 = blockIdx.x * 128, n0 = blockIdx.y * 128;
  int wave = tid >> 6, lane = tid & 63;
  int wm = (wave >> 1) * 64, wn = (wave & 1) * 64;
  int r16 = lane & 15, quad = lane >> 4;

  f32x4 acc[4][4] = {};

  int srow0 = wave * 32 + (lane >> 2);
  int srow1 = srow0 + 16;
  int c4    = lane & 3;
  int q0 = c4 ^ ((srow0 >> 1) & 3);
  int q1 = c4 ^ ((srow1 >> 1) & 3);
  const u16* Ag0 = A + (size_t)(m0 + srow0) * 1024 + q0 * 8;
  const u16* Ag1 = A + (size_t)(m0 + srow1) * 1024 + q1 * 8;
  const u16* Bg0 = W + (size_t)(n0 + srow0) * 1024 + q0 * 8;
  const u16* Bg1 = W + (size_t)(n0 + srow1) * 1024 + q1 * 8;
  int ldsOff0 = wave * 1024;        // u16 offset within one 8KB buffer
  int ldsOff1 = wave * 1024 + 512;

  int aoff[4], boff[4];
#pragma unroll
  for (int mt = 0; mt < 4; ++mt) {
    int r = wm + mt * 16 + r16;
    aoff[mt] = r * 32 + (quad ^ ((r >> 1) & 3)) * 8;
  }
#pragma unroll
  for (int nt = 0; nt < 4; ++nt) {
    int r = wn + nt * 16 + r16;
    boff[nt] = r * 32 + (quad ^ ((r >> 1) & 3)) * 8;
  }

#define ISSUE_TILE(t, buf)                                                              \
  do {                                                                                  \
    int _o = (buf) * 4096, _k = (t) * 32;                                               \
    __builtin_amdgcn_global_load_lds(GLB_PTR(Ag0 + _k), LDS_PTR(Asm + _o + ldsOff0), 16, 0, 0); \
    __builtin_amdgcn_global_load_lds(GLB_PTR(Ag1 + _k), LDS_PTR(Asm + _o + ldsOff1), 16, 0, 0); \
    __builtin_amdgcn_global_load_lds(GLB_PTR(Bg0 + _k), LDS_PTR(Bsm + _o + ldsOff0), 16, 0, 0); \
    __builtin_amdgcn_global_load_lds(GLB_PTR(Bg1 + _k), LDS_PTR(Bsm + _o + ldsOff1), 16, 0, 0); \
  } while (0)

  ISSUE_TILE(0, 0);
  ISSUE_TILE(1, 1);
  ISSUE_TILE(2, 2);

  int cur = 0;
  for (int i = 0; i < 32; ++i) {
    if (i < 30)       asm volatile("s_waitcnt vmcnt(8)" ::: "memory");
    else if (i == 30) asm volatile("s_waitcnt vmcnt(4)" ::: "memory");
    else              asm volatile("s_waitcnt vmcnt(0)" ::: "memory");
    __builtin_amdgcn_s_barrier();   // all waves' tile-i data landed

    const u16* As = Asm + cur * 4096;
    const u16* Bs = Bsm + cur * 4096;
    bf16x8 af[4], bfm[4];
#pragma unroll
    for (int mt = 0; mt < 4; ++mt) af[mt] = *(const bf16x8*)&As[aoff[mt]];
#pragma unroll
    for (int nt = 0; nt < 4; ++nt) bfm[nt] = *(const bf16x8*)&Bs[boff[nt]];
#pragma unroll
    for (int mt = 0; mt < 4; ++mt)
#pragma unroll
      for (int nt = 0; nt < 4; ++nt)
        acc[mt][nt] = __builtin_amdgcn_mfma_f32_16x16x32_bf16(af[mt], bfm[nt], acc[mt][nt], 0, 0, 0);

    asm volatile("s_waitcnt lgkmcnt(0)" ::: "memory");  // my ds_reads done
    __builtin_amdgcn_s_barrier();                       // everyone's reads done
    if (i + 3 < 32) ISSUE_TILE(i + 3, cur);             // re-target freed buffer
    cur = (cur == 2) ? 0 : cur + 1;
  }
#undef ISSUE_TILE

  // epilogue: C/D layout col=lane&15, row=quad*4+reg  [verified m89/m91]
#pragma unroll
  for (int mt = 0; mt < 4; ++mt) {
#pragma unroll
    for (int nt = 0; nt < 4; ++nt) {
#pragma unroll
      for (int rg = 0; rg < 4; ++rg) {
        int row = m0 + wm + mt * 16 + quad * 4 + rg;
        int col = n0 + wn + nt * 16 + r16;
        float v = acc[mt][nt][rg];
        if (ACT == 1) v = 1.f / (1.f + __expf(-v));
        else if (ACT == 2) v = -(fmaxf(-v, 0.f) + log1pf(expf(-fabsf(v)))) - 1e-4f;
        size_t idx = (size_t)row * 1024 + col;
        if (OBF) ((u16*)Optr)[idx] = f2bf(v);
        else     ((float*)Optr)[idx] = v;
      }
    }
  }
}

// K2: four projection GEMMs in one launch (grid.z selects matrix)
__global__ __launch_bounds__(256) void gemm4_bt(
    const u16* __restrict__ xr, const u16* __restrict__ xk,
    const u16* __restrict__ xv, const u16* __restrict__ xw,
    const u16* __restrict__ Wr, const u16* __restrict__ Wk,
    const u16* __restrict__ Wv, const u16* __restrict__ Ww,
    u16* __restrict__ r, u16* __restrict__ k,
    u16* __restrict__ v, float* __restrict__ w) {
  __shared__ __align__(16) u16 Asm[3 * 4096];
  __shared__ __align__(16) u16 Bsm[3 * 4096];
  switch (blockIdx.z) {
    case 0:  gemm_core<1, 1>(xr, Wr, r, Asm, Bsm); break;   // r = sigmoid, bf16
    case 1:  gemm_core<0, 1>(xk, Wk, k, Asm, Bsm); break;   // k bf16
    case 2:  gemm_core<0, 1>(xv, Wv, v, Asm, Bsm); break;   // v bf16
    default: gemm_core<2, 0>(xw, Ww, w, Asm, Bsm); break;   // w fp32 (decay path)
  }
}

// K6: output GEMM
__global__ __launch_bounds__(256) void gemm_out(
    const u16* __restrict__ A, const u16* __restrict__ W, float* __restrict__ O) {
  __shared__ __align__(16) u16 Asm[3 * 4096];
  __shared__ __align__(16) u16 Bsm[3 * 4096];
  gemm_core<0, 0>(A, W, O, Asm, Bsm);
}

// ---------------- K3: single-pass intra-chunk scan (2-step batching) --------
// Block = (chunk c, b*16+h), 256 threads = 4 i-groups x 64 j.
// Loader roles: w0 -> r (and rd/decay), w1 -> k(+euk), w2 -> v, w3 -> ew.
// 4-slot LDS ring (slot = t&3): stage steps tt+2,tt+3 while computing tt,tt+1.
// One barrier per 2 steps. o-stores deferred one interval (part slots).
__global__ __launch_bounds__(256) void scan_intra(
    const u16* __restrict__ rb, const u16* __restrict__ kb,
    const u16* __restrict__ vb, const float* __restrict__ wb,
    const float* __restrict__ u,
    float* __restrict__ o, u16* __restrict__ rd,
    float* __restrict__ U, float* __restrict__ Dc) {
  int c = blockIdx.x, bh = blockIdx.y;
  int b = bh >> 4, h = bh & 15;
  int tid = threadIdx.x, ig = tid >> 6, j = tid & 63;

  __shared__ __align__(16) float4 combo[4][64];  // per-i: (r, k, exp(u+k), exp(w))
  __shared__ float vs_[4][64];
  __shared__ float part[4][4][64];

  float s[16];
#pragma unroll
  for (int ii = 0; ii < 16; ++ii) s[ii] = 0.f;

  size_t base = ((size_t)(b * 1024 + c * 64)) * 1024 + h * 64 + j;
  float dloc = 1.0f;
  float uval = (ig == 1) ? u[h * 64 + j] : 0.f;

  // prologue: stage steps 0,1 into slots 0,1
#pragma unroll
  for (int p = 0; p < 2; ++p) {
    size_t idx = base + (size_t)p * 1024;
    if (ig == 0)      combo[p][j].x = bf2f(rb[idx]);
    else if (ig == 1) { float kv = bf2f(kb[idx]); combo[p][j].y = kv; combo[p][j].z = __expf(uval + kv); }
    else if (ig == 2) vs_[p][j] = bf2f(vb[idx]);
    else              combo[p][j].w = __expf(wb[idx]);
  }
  __syncthreads();

  for (int tt = 0; tt < 64; tt += 2) {
    // stage steps tt+2, tt+3 into their slots (disjoint from compute slots)
    if (tt + 2 < 64) {
#pragma unroll
      for (int p = 0; p < 2; ++p) {
        int t2 = tt + 2 + p, sl = t2 & 3;
        size_t idx = base + (size_t)t2 * 1024;
        if (ig == 0)      combo[sl][j].x = bf2f(rb[idx]);
        else if (ig == 1) { float kv = bf2f(kb[idx]); combo[sl][j].y = kv; combo[sl][j].z = __expf(uval + kv); }
        else if (ig == 2) vs_[sl][j] = bf2f(vb[idx]);
        else              combo[sl][j].w = __expf(wb[idx]);
      }
    }
    // compute steps tt, tt+1 (slots staged last interval, barrier crossed)
#pragma unroll
    for (int p = 0; p < 2; ++p) {
      int t = tt + p, sl = t & 3;
      float vj = vs_[sl][j];
      float acc = 0.f;
#pragma unroll
      for (int ii = 0; ii < 16; ++ii) {
        float4 cb = combo[sl][ig * 16 + ii];  // broadcast b128
        float tmp = fmaf(cb.z, vj, s[ii]);    // s + exp(u+k)*v
        acc = fmaf(cb.x, tmp, acc);           // += r * (...)
        s[ii] = fmaf(cb.w, s[ii], cb.y * vj); // s = exp(w)*s + k*v
      }
      part[sl][ig][j] = acc;
      if (ig == 0) {
        rd[base + (size_t)t * 1024] = f2bf(combo[sl][j].x * dloc);
        dloc *= combo[sl][j].w;
      }
    }
    // store o for steps tt-2, tt-1 (parts complete since last barrier)
    if (tt >= 2) {
      if (ig == 2) {
        int t = tt - 2, sl = t & 3;
        o[base + (size_t)t * 1024] =
            part[sl][0][j] + part[sl][1][j] + part[sl][2][j] + part[sl][3][j];
      } else if (ig == 3) {
        int t = tt - 1, sl = t & 3;
        o[base + (size_t)t * 1024] =
            part[sl][0][j] + part[sl][1][j] + part[sl][2][j] + part[sl][3][j];
      }
    }
    __syncthreads();
  }
  // final two steps' o (parts written in last interval, barrier crossed)
  if (ig == 2) {
    o[base + (size_t)62 * 1024] = part[2][0][j] + part[2][1][j] + part[2][2][j] + part[2][3][j];
  } else if (ig == 3) {
    o[base + (size_t)63 * 1024] = part[3][0][j] + part[3][1][j] + part[3][2][j] + part[3][3][j];
  }

  float* Ug = U + (size_t)(bh * 16 + c) * 4096;
#pragma unroll
  for (int ii = 0; ii < 16; ++ii) Ug[(ig * 16 + ii) * 64 + j] = s[ii];
  if (ig == 0) Dc[(bh * 16 + c) * 64 + j] = dloc;
}

// ---------------- K4: chunk-state propagation (per-element parallel) --------
__global__ __launch_bounds__(256) void state_prop(
    float* __restrict__ U, const float* __restrict__ Dc) {
  int bh  = blockIdx.x >> 4;
  int e   = (blockIdx.x & 15) * 256 + threadIdx.x;  // 0..4095
  int i   = e >> 6;                                 // state row (decay index)
  float acc = 0.f;
  for (int c = 0; c < 16; ++c) {
    float* Ug = U + (size_t)(bh * 16 + c) * 4096 + e;
    float d = Dc[(bh * 16 + c) * 64 + i];
    float uv = *Ug;
    *Ug = acc;                      // write S_c (chunk-initial state)
    acc = fmaf(d, acc, uv);         // S_{c+1} = D_c*S_c + U_c
  }
}

// ---------------- K5: O = o_intra + RD@S_c (MFMA) + group-LN + gate --------
// Block (c, bh), 256 threads = 4 waves. Wave w owns t-strip [w*16, w*16+16).
// S_c (fp32, [i][j]) transposed to bf16 LDS Sb[j][i] (pad 72 for b128 align).
// A = rd[t][i] (bf16, global, K-contiguous). D[m=t][n=j] = sum_i rd*S.
__global__ __launch_bounds__(256) void inter_ln(
    const float* __restrict__ o, const u16* __restrict__ rd,
    const u16* __restrict__ rb, const float* __restrict__ U,
    const float* __restrict__ lnw, const float* __restrict__ lnb,
    u16* __restrict__ oh) {
  int c = blockIdx.x, bh = blockIdx.y;
  int b = bh >> 4, h = bh & 15;
  int tid = threadIdx.x, wave = tid >> 6, lane = tid & 63;
  int l15 = lane & 15, quad = lane >> 4;

  __shared__ __align__(16) u16 Sb[64][72];   // Sb[j][i] = S_c[i][j] (bf16)

  const float* Sg = U + (size_t)(bh * 16 + c) * 4096;
#pragma unroll
  for (int q = 0; q < 16; ++q) {
    int e = q * 256 + tid;
    Sb[e & 63][e >> 6] = f2bf(Sg[e]);
  }
  __syncthreads();

  size_t rbase = ((size_t)(b * 1024 + c * 64)) * 1024 + h * 64;

  // A fragments: A[m=l15][k=quad*8+idx] (+32 for kt=1), m-strip = wave*16
  const u16* rdg = rd + rbase + (size_t)(wave * 16 + l15) * 1024 + quad * 8;
  bf16x8 af0 = *(const bf16x8*)(rdg);
  bf16x8 af1 = *(const bf16x8*)(rdg + 32);

  f32x4 acc[4] = {};
#pragma unroll
  for (int nt = 0; nt < 4; ++nt) {
    const u16* bp = &Sb[nt * 16 + l15][quad * 8];
    bf16x8 b0 = *(const bf16x8*)bp;
    bf16x8 b1 = *(const bf16x8*)(bp + 32);
    acc[nt] = __builtin_amdgcn_mfma_f32_16x16x32_bf16(af0, b0, acc[nt], 0, 0, 0);
    acc[nt] = __builtin_amdgcn_mfma_f32_16x16x32_bf16(af1, b1, acc[nt], 0, 0, 0);
  }

  // epilogue: row t = wave*16 + quad*4 + rg; col j = nt*16 + l15.
#pragma unroll
  for (int rg = 0; rg < 4; ++rg) {
    int t = wave * 16 + quad * 4 + rg;
    size_t rowb = rbase + (size_t)t * 1024;
    float v[4];
    float s1 = 0.f, s2 = 0.f;
#pragma unroll
    for (int nt = 0; nt < 4; ++nt) {
      v[nt] = acc[nt][rg] + o[rowb + nt * 16 + l15];
      s1 += v[nt];
      s2 += v[nt] * v[nt];
    }
#pragma unroll
    for (int m = 1; m < 16; m <<= 1) {   // reduce across the quad's 16 lanes
      s1 += __shfl_xor(s1, m, 64);
      s2 += __shfl_xor(s2, m, 64);
    }
    float mu  = s1 * (1.f / 64.f);
    float var = s2 * (1.f / 64.f) - mu * mu;
    float rstd = rsqrtf(var + 1e-5f);
#pragma unroll
    for (int nt = 0; nt < 4; ++nt) {
      int jj = nt * 16 + l15;
      float nv = (v[nt] - mu) * rstd;
      float val = (nv * lnw[jj] + lnb[jj]) * bf2f(rb[rowb + jj]);
      oh[rowb + jj] = f2bf(val);
    }
  }
}

// ---------------- launch -----------------------------------------------------
extern "C" void kernel_launch(void* const* d_in, const int* in_sizes, int n_in,
                              void* d_out, int out_size, void* d_ws, size_t ws_size,
                              hipStream_t stream) {
  const float* x    = (const float*)d_in[0];
  const float* W_r  = (const float*)d_in[1];
  const float* W_k  = (const float*)d_in[2];
  const float* W_v  = (const float*)d_in[3];
  const float* W_w  = (const float*)d_in[4];
  const float* W_o  = (const float*)d_in[5];
  const float* u    = (const float*)d_in[6];
  const float* tm_r = (const float*)d_in[7];
  const float* tm_k = (const float*)d_in[8];
  const float* tm_v = (const float*)d_in[9];
  const float* tm_w = (const float*)d_in[10];
  const float* ln_w = (const float*)d_in[11];
  const float* ln_b = (const float*)d_in[12];
  float* out = (float*)d_out;

  char* ws = (char*)d_ws;
  u16* xr = (u16*)(ws + (size_t)0 * MB);
  u16* xk = (u16*)(ws + (size_t)8 * MB);
  u16* xv = (u16*)(ws + (size_t)16 * MB);
  u16* xw = (u16*)(ws + (size_t)24 * MB);
  u16* Wb = (u16*)(ws + (size_t)32 * MB);   // 5 x 2MB: Wr,Wk,Wv,Ww,Wo
  u16* Wrb = Wb;
  u16* Wkb = (u16*)(ws + (size_t)34 * MB);
  u16* Wvb = (u16*)(ws + (size_t)36 * MB);
  u16* Wwb = (u16*)(ws + (size_t)38 * MB);
  u16* Wob = (u16*)(ws + (size_t)40 * MB);
  u16*   rbuf = (u16*)(ws + (size_t)48 * MB);    // 8MB bf16
  u16*   kbuf = (u16*)(ws + (size_t)56 * MB);    // 8MB bf16
  u16*   vbuf = (u16*)(ws + (size_t)64 * MB);    // 8MB bf16
  float* wbuf = (float*)(ws + (size_t)72 * MB);  // 16MB fp32 (decay path)
  float* obuf = (float*)(ws + (size_t)88 * MB);  // 16MB fp32 o_intra
  u16*  rdbuf = (u16*)(ws + (size_t)104 * MB);   // 8MB bf16
  float* Ubuf  = (float*)(ws + (size_t)112 * MB);// 16MB (S_c after state_prop)
  float* Dcbuf = (float*)(ws + (size_t)128 * MB);// 256KB
  u16*   ohbuf = (u16*)(ws + (size_t)129 * MB);  // 8MB

  prep_w<<<10240, 256, 0, stream>>>(W_r, W_k, W_v, W_w, W_o, (u32*)Wb);
  prep_mix<<<8192, 256, 0, stream>>>(x, tm_r, tm_k, tm_v, tm_w,
                                     (u32*)xr, (u32*)xk, (u32*)xv, (u32*)xw);
  gemm4_bt<<<dim3(32, 8, 4), 256, 0, stream>>>(xr, xk, xv, xw,
                                               Wrb, Wkb, Wvb, Wwb,
                                               rbuf, kbuf, vbuf, wbuf);
  scan_intra<<<dim3(16, 64), 256, 0, stream>>>(rbuf, kbuf, vbuf, wbuf, u,
                                               obuf, rdbuf, Ubuf, Dcbuf);
  state_prop<<<1024, 256, 0, stream>>>(Ubuf, Dcbuf);
  inter_ln<<<dim3(16, 64), 256, 0, stream>>>(obuf, rdbuf, rbuf, Ubuf,
                                             ln_w, ln_b, ohbuf);
  gemm_out<<<dim3(32, 8, 1), 256, 0, stream>>>(ohbuf, Wob, out);
}